// Round 1
// baseline (280.040 us; speedup 1.0000x reference)
//
#include <hip/hip_runtime.h>

#define F0 128
#define F1 64
#define F2 32

__device__ __forceinline__ int rfl(int v) { return __builtin_amdgcn_readfirstlane(v); }

// bf16 helpers (RNE)
__device__ __forceinline__ unsigned short f2b(float f) {
    unsigned u = __float_as_uint(f);
    return (unsigned short)((u + 0x7fffu + ((u >> 16) & 1u)) >> 16);
}
__device__ __forceinline__ float b2f(unsigned short u) {
    return __uint_as_float(((unsigned)u) << 16);
}

// accumulate 8 bf16 (packed in a uint4) into 8 float accumulators
__device__ __forceinline__ void acc8(float* a, uint4 v) {
    a[0] += __uint_as_float(v.x << 16);
    a[1] += __uint_as_float(v.x & 0xffff0000u);
    a[2] += __uint_as_float(v.y << 16);
    a[3] += __uint_as_float(v.y & 0xffff0000u);
    a[4] += __uint_as_float(v.z << 16);
    a[5] += __uint_as_float(v.z & 0xffff0000u);
    a[6] += __uint_as_float(v.w << 16);
    a[7] += __uint_as_float(v.w & 0xffff0000u);
}

// ---------------- degree (int4-vectorized dst reads) ----------------
__global__ void deg_count(const int* __restrict__ dst, int* __restrict__ deg, int E) {
    int q = blockIdx.x * blockDim.x + threadIdx.x;
    int e = q << 2;
    if (e + 3 < E) {
        int4 d = *(const int4*)(dst + e);
        atomicAdd(&deg[d.x], 1);
        atomicAdd(&deg[d.y], 1);
        atomicAdd(&deg[d.z], 1);
        atomicAdd(&deg[d.w], 1);
    } else if (e < E) {
        for (int k = e; k < E; ++k) atomicAdd(&deg[dst[k]], 1);
    }
}

// ---------------- scan (3 kernels; round-9 post-mortem: single-block fused scan
// was 135 us latency-bound on one CU — multi-block version is ~5 us) ----------------
__global__ void scan1(const int* __restrict__ deg, float* __restrict__ dinv,
                      int* __restrict__ rowptr, int* __restrict__ bsum, int N) {
    __shared__ int s[256];
    int i = blockIdx.x * 256 + threadIdx.x;
    int v = (i < N) ? deg[i] : 0;
    if (i < N) dinv[i] = rsqrtf((float)(v + 1));  // +1 self-loop
    s[threadIdx.x] = v;
    __syncthreads();
    for (int off = 1; off < 256; off <<= 1) {
        int t = 0;
        if (threadIdx.x >= off) t = s[threadIdx.x - off];
        __syncthreads();
        if (threadIdx.x >= off) s[threadIdx.x] += t;
        __syncthreads();
    }
    if (i < N) rowptr[i] = s[threadIdx.x] - v;
    if (threadIdx.x == 255) bsum[blockIdx.x] = s[255];
}

__global__ void scan2(int* __restrict__ bsum, int* __restrict__ boff, int nb) {
    __shared__ int s[256];
    int v = (threadIdx.x < nb) ? bsum[threadIdx.x] : 0;
    s[threadIdx.x] = v;
    __syncthreads();
    for (int off = 1; off < 256; off <<= 1) {
        int t = 0;
        if (threadIdx.x >= off) t = s[threadIdx.x - off];
        __syncthreads();
        if (threadIdx.x >= off) s[threadIdx.x] += t;
        __syncthreads();
    }
    if (threadIdx.x < nb) boff[threadIdx.x] = s[threadIdx.x] - v;
}

__global__ void scan3(int* __restrict__ rowptr, const int* __restrict__ boff,
                      int* __restrict__ cursor, int N) {
    int i = blockIdx.x * 256 + threadIdx.x;
    if (i < N) {
        int v = rowptr[i] + boff[blockIdx.x];
        rowptr[i] = v;
        cursor[i] = v;
    }
}

// ---------------- bucket, XCD-pinned by dst partition (blockIdx&7);
// int4-vectorized dst reads (8 passes over dst -> 4x fewer load instrs) ----------------
__global__ __launch_bounds__(256) void bucket8(const int* __restrict__ src,
                                               const int* __restrict__ dst,
                                               int* __restrict__ cursor,
                                               int* __restrict__ csr, int E, int N) {
    int part = blockIdx.x & 7;
    int g = blockIdx.x >> 3;
    int G = gridDim.x >> 3;
    int plo = (int)(((long long)N * part) >> 3);
    int phi = (int)(((long long)N * (part + 1)) >> 3);
    int E4 = E >> 2;
    for (int q = g * 256 + threadIdx.x; q < E4; q += G * 256) {
        int4 d = ((const int4*)dst)[q];
        int e = q << 2;
        if (d.x >= plo && d.x < phi) { int p = atomicAdd(&cursor[d.x], 1); csr[p] = src[e]; }
        if (d.y >= plo && d.y < phi) { int p = atomicAdd(&cursor[d.y], 1); csr[p] = src[e + 1]; }
        if (d.z >= plo && d.z < phi) { int p = atomicAdd(&cursor[d.z], 1); csr[p] = src[e + 2]; }
        if (d.w >= plo && d.w < phi) { int p = atomicAdd(&cursor[d.w], 1); csr[p] = src[e + 3]; }
    }
    if (g == 0 && threadIdx.x < (E & 3)) {
        int e = (E & ~3) + threadIdx.x;
        int d = dst[e];
        if (d >= plo && d < phi) { int p = atomicAdd(&cursor[d], 1); csr[p] = src[e]; }
    }
}

// ---------------- GEMM1: xws1b = bf16((x @ W1) * dinv[row])   [N,128]x[128,64] -------
// k-loop bound `kb` is a RUNTIME arg so the compiler cannot fully unroll
// (round-5 post-mortem: full unroll -> 256 VGPR -> 750 MB scratch spill).
__global__ __launch_bounds__(256) void gemm1(const float* __restrict__ x,
                                             const float* __restrict__ W1,
                                             const float* __restrict__ dinv,
                                             unsigned short* __restrict__ xws1b,
                                             int N, int kb) {
    __shared__ float sx[64][132];
    __shared__ float sW[64][64];
    int tid = threadIdx.x;
    int row0 = blockIdx.x * 64;

    for (int i = tid; i < 2048; i += 256) {
        int r = i >> 5, kq = i & 31;
        int gr = row0 + r;
        float4 v = make_float4(0.f, 0.f, 0.f, 0.f);
        if (gr < N) v = ((const float4*)(x + (size_t)gr * F0))[kq];
        *(float4*)(&sx[r][kq << 2]) = v;
    }

    int tx = tid & 15, ty = tid >> 4;
    int c0 = tx * 4, r0 = ty * 4;
    float acc[4][4] = {};

    const float4* W4 = (const float4*)W1;
    float4* sW4 = (float4*)(&sW[0][0]);

    for (int p = 0; p < 2; ++p) {
        if (p) __syncthreads();
        for (int i = tid; i < 1024; i += 256) sW4[i] = W4[p * 1024 + i];
        __syncthreads();
        int kbase = p * 64;
        for (int k = 0; k < kb; k += 4) {
            float a[4][4], b[4][4];
            #pragma unroll
            for (int rr = 0; rr < 4; ++rr)
                *(float4*)&a[rr][0] = *(const float4*)&sx[r0 + rr][kbase + k];
            #pragma unroll
            for (int j = 0; j < 4; ++j)
                *(float4*)&b[j][0] = *(const float4*)&sW[k + j][c0];
            #pragma unroll
            for (int j = 0; j < 4; ++j)
                #pragma unroll
                for (int rr = 0; rr < 4; ++rr)
                    #pragma unroll
                    for (int cc = 0; cc < 4; ++cc)
                        acc[rr][cc] += a[rr][j] * b[j][cc];
        }
    }

    #pragma unroll
    for (int rr = 0; rr < 4; ++rr) {
        int gr = row0 + r0 + rr;
        if (gr < N) {
            float s = dinv[gr];
            ushort4 o;
            o.x = f2b(acc[rr][0] * s); o.y = f2b(acc[rr][1] * s);
            o.z = f2b(acc[rr][2] * s); o.w = f2b(acc[rr][3] * s);
            *(ushort4*)&xws1b[gr * F1 + c0] = o;
        }
    }
}

// ---- gather1 + gemm2 fused. Round-13 rework: wide gathers.
// Old: 64 lanes x ushort (2 B/lane) per neighbor row + 8 broadcast csr loads
//      => ~32 VMEM instrs / 8 edges. VMEM-issue-bound, not BW-bound
//      (total gather traffic ~102 MB from a 6.4 MB L2/L3-resident table).
// New: lane loads uint4 = 8 bf16 (16 B/lane); 8 lanes cover one 128 B row,
//      wave covers 8 edges per load instr; per-lane csr load (8 distinct
//      addrs, 1 instr). => 2 VMEM instrs / 8 edges. Cross-group shfl_xor
//      reduction (8,16,32) once per node. ----
__global__ __launch_bounds__(256) void gather1f(const int* __restrict__ csr,
                                                const int* __restrict__ rowptr,
                                                const int* __restrict__ deg,
                                                const float* __restrict__ dinv,
                                                const unsigned short* __restrict__ xb,
                                                const float* __restrict__ b1,
                                                const float* __restrict__ W2,
                                                unsigned short* __restrict__ xws2b,
                                                int N, int kh) {
    __shared__ float sW2[F1][F2];    // 8 KB
    __shared__ float h1s[4][F1];     // 1 KB
    int tid = threadIdx.x;
    for (int i = tid; i < (F1 * F2) / 4; i += 256)
        ((float4*)&sW2[0][0])[i] = ((const float4*)W2)[i];
    __syncthreads();

    int wv = tid >> 6, lane = tid & 63;
    int node = blockIdx.x * 4 + wv;
    if (node >= N) return;
    int start = rfl(rowptr[node]);
    int cnt = rfl(deg[node]);

    int grp = lane >> 3;           // edge slot 0..7
    int fb = (lane & 7) << 3;      // feature base 0..56 (8 features/lane)

    float acc[8] = {};
    for (int j = 0; j < cnt; j += 8) {
        int e = j + grp;
        if (e < cnt) {
            int s = csr[start + e];
            uint4 v = *(const uint4*)(xb + (size_t)s * F1 + fb);
            acc8(acc, v);
        }
    }
    if (grp == 0) {  // self-loop term, counted exactly once
        uint4 v = *(const uint4*)(xb + (size_t)node * F1 + fb);
        acc8(acc, v);
    }
    #pragma unroll
    for (int off = 8; off < 64; off <<= 1)
        #pragma unroll
        for (int i = 0; i < 8; ++i)
            acc[i] += __shfl_xor(acc[i], off, 64);

    float dd = dinv[node];
    if (lane < 8) {   // lanes 0..7 cover all 64 features (8 each)
        float4 bA = *(const float4*)&b1[fb];
        float4 bB = *(const float4*)&b1[fb + 4];
        float4 p, q;
        p.x = fmaxf(dd * acc[0] + bA.x, 0.f);
        p.y = fmaxf(dd * acc[1] + bA.y, 0.f);
        p.z = fmaxf(dd * acc[2] + bA.z, 0.f);
        p.w = fmaxf(dd * acc[3] + bA.w, 0.f);
        q.x = fmaxf(dd * acc[4] + bB.x, 0.f);
        q.y = fmaxf(dd * acc[5] + bB.y, 0.f);
        q.z = fmaxf(dd * acc[6] + bB.z, 0.f);
        q.w = fmaxf(dd * acc[7] + bB.w, 0.f);
        *(float4*)&h1s[wv][fb] = p;
        *(float4*)&h1s[wv][fb + 4] = q;
    }

    // GEMV: h1[64] @ W2[64][32], split k across wave halves (unchanged)
    int c = lane & 31, half = lane >> 5;
    int k0 = half * 32;
    float d0 = 0.f, d1 = 0.f, d2 = 0.f, d3 = 0.f;
    for (int k = 0; k < kh; k += 4) {
        d0 += h1s[wv][k0 + k]     * sW2[k0 + k][c];
        d1 += h1s[wv][k0 + k + 1] * sW2[k0 + k + 1][c];
        d2 += h1s[wv][k0 + k + 2] * sW2[k0 + k + 2][c];
        d3 += h1s[wv][k0 + k + 3] * sW2[k0 + k + 3][c];
    }
    float dot = (d0 + d1) + (d2 + d3);
    dot += __shfl_down(dot, 32, 64);
    if (half == 0) xws2b[node * F2 + c] = f2b(dot * dd);
}

// ---- gather2 + gemm3 fused. Same wide-gather rework: 4 lanes cover one
// 64 B row (uint4 each), wave covers 16 edges per load instr. `out` written
// with NON-TEMPORAL stores: write-once/never-read — avoid L2 RFO
// (round-12 counters: gather2f FETCH 35.4 MB ≈ inputs + 25.6 MB out RFO). ----
__global__ __launch_bounds__(256) void gather2f(const int* __restrict__ csr,
                                                const int* __restrict__ rowptr,
                                                const int* __restrict__ deg,
                                                const float* __restrict__ dinv,
                                                const unsigned short* __restrict__ xb,
                                                const float* __restrict__ b2,
                                                const float* __restrict__ Wl,
                                                const float* __restrict__ bl,
                                                float* __restrict__ out, int N, int kh) {
    __shared__ float sWl[F2][F0];    // 16 KB
    __shared__ float h2s[4][F2];     // 512 B
    int tid = threadIdx.x;
    for (int i = tid; i < (F2 * F0) / 4; i += 256)
        ((float4*)&sWl[0][0])[i] = ((const float4*)Wl)[i];
    __syncthreads();

    int wv = tid >> 6, lane = tid & 63;
    int node = blockIdx.x * 4 + wv;
    if (node >= N) return;
    int start = rfl(rowptr[node]);
    int cnt = rfl(deg[node]);

    int grp = lane >> 2;           // edge slot 0..15
    int fb = (lane & 3) << 3;      // feature base 0,8,16,24 (8 features/lane)

    float acc[8] = {};
    for (int j = 0; j < cnt; j += 16) {
        int e = j + grp;
        if (e < cnt) {
            int s = csr[start + e];
            uint4 v = *(const uint4*)(xb + (size_t)s * F2 + fb);
            acc8(acc, v);
        }
    }
    if (grp == 0) {  // self-loop term
        uint4 v = *(const uint4*)(xb + (size_t)node * F2 + fb);
        acc8(acc, v);
    }
    #pragma unroll
    for (int off = 4; off < 64; off <<= 1)
        #pragma unroll
        for (int i = 0; i < 8; ++i)
            acc[i] += __shfl_xor(acc[i], off, 64);

    float dd = dinv[node];
    if (lane < 4) {   // lanes 0..3 cover all 32 features (8 each)
        float4 bA = *(const float4*)&b2[fb];
        float4 bB = *(const float4*)&b2[fb + 4];
        float4 p, q;
        p.x = fmaxf(dd * acc[0] + bA.x, 0.f);
        p.y = fmaxf(dd * acc[1] + bA.y, 0.f);
        p.z = fmaxf(dd * acc[2] + bA.z, 0.f);
        p.w = fmaxf(dd * acc[3] + bA.w, 0.f);
        q.x = fmaxf(dd * acc[4] + bB.x, 0.f);
        q.y = fmaxf(dd * acc[5] + bB.y, 0.f);
        q.z = fmaxf(dd * acc[6] + bB.z, 0.f);
        q.w = fmaxf(dd * acc[7] + bB.w, 0.f);
        *(float4*)&h2s[wv][fb] = p;
        *(float4*)&h2s[wv][fb + 4] = q;
    }

    // final GEMV: h2[32] @ Wl[32][128] + bl (unchanged)
    float e0 = 0.f, e1 = 0.f, f0 = 0.f, f1 = 0.f;
    for (int k = 0; k < kh; k += 2) {
        float hk0 = h2s[wv][k], hk1 = h2s[wv][k + 1];
        e0 += hk0 * sWl[k][lane];
        e1 += hk1 * sWl[k + 1][lane];
        f0 += hk0 * sWl[k][lane + 64];
        f1 += hk1 * sWl[k + 1][lane + 64];
    }
    size_t ob = (size_t)node * F0;
    __builtin_nontemporal_store((e0 + e1) + bl[lane],      &out[ob + lane]);
    __builtin_nontemporal_store((f0 + f1) + bl[lane + 64], &out[ob + lane + 64]);
}

extern "C" void kernel_launch(void* const* d_in, const int* in_sizes, int n_in,
                              void* d_out, int out_size, void* d_ws, size_t ws_size,
                              hipStream_t stream) {
    const float* x  = (const float*)d_in[0];
    const int*   ei = (const int*)d_in[1];
    const float* W1 = (const float*)d_in[2];
    const float* b1 = (const float*)d_in[3];
    const float* W2 = (const float*)d_in[4];
    const float* b2 = (const float*)d_in[5];
    const float* Wl = (const float*)d_in[6];
    const float* bl = (const float*)d_in[7];
    float* out = (float*)d_out;

    const int N = in_sizes[0] / F0;   // 50000
    const int E = in_sizes[1] / 2;    // 800000
    const int* src = ei;
    const int* dst = ei + E;
    const int NB = (N + 255) / 256;   // 196

    char* ws = (char*)d_ws;
    size_t off = 0;
    auto alloc = [&](size_t bytes) {
        void* p = ws + off;
        off += (bytes + 255) & ~(size_t)255;
        return p;
    };
    int*            deg    = (int*)alloc((size_t)N * 4);
    float*          dinv   = (float*)alloc((size_t)N * 4);
    int*            rowptr = (int*)alloc((size_t)N * 4);
    int*            cursor = (int*)alloc((size_t)N * 4);
    int*            bsum   = (int*)alloc((size_t)NB * 4);
    int*            boff   = (int*)alloc((size_t)NB * 4);
    int*            csr    = (int*)alloc((size_t)E * 4);
    unsigned short* xws1b  = (unsigned short*)alloc((size_t)N * F1 * 2);
    unsigned short* xws2b  = (unsigned short*)alloc((size_t)N * F2 * 2);

    hipMemsetAsync(deg, 0, (size_t)N * 4, stream);
    const int EQ = (E + 3) / 4;
    deg_count<<<(EQ + 255) / 256, 256, 0, stream>>>(dst, deg, E);
    scan1<<<NB, 256, 0, stream>>>(deg, dinv, rowptr, bsum, N);
    scan2<<<1, 256, 0, stream>>>(bsum, boff, NB);
    scan3<<<NB, 256, 0, stream>>>(rowptr, boff, cursor, N);
    bucket8<<<1024, 256, 0, stream>>>(src, dst, cursor, csr, E, N);

    gemm1<<<(N + 63) / 64, 256, 0, stream>>>(x, W1, dinv, xws1b, N, 64);
    gather1f<<<(N + 3) / 4, 256, 0, stream>>>(csr, rowptr, deg, dinv, xws1b, b1, W2, xws2b, N, 32);
    gather2f<<<(N + 3) / 4, 256, 0, stream>>>(csr, rowptr, deg, dinv, xws2b, b2, Wl, bl, out, N, 32);
}

// Round 2
// 261.073 us; speedup vs baseline: 1.0727x; 1.0727x over previous
//
#include <hip/hip_runtime.h>

#define F0 128
#define F1 64
#define F2 32

__device__ __forceinline__ int rfl(int v) { return __builtin_amdgcn_readfirstlane(v); }

// bf16 helpers (RNE)
__device__ __forceinline__ unsigned short f2b(float f) {
    unsigned u = __float_as_uint(f);
    return (unsigned short)((u + 0x7fffu + ((u >> 16) & 1u)) >> 16);
}
__device__ __forceinline__ float b2f(unsigned short u) {
    return __uint_as_float(((unsigned)u) << 16);
}

// accumulate 8 bf16 (packed in a uint4) into 8 float accumulators
__device__ __forceinline__ void acc8(float* a, uint4 v) {
    a[0] += __uint_as_float(v.x << 16);
    a[1] += __uint_as_float(v.x & 0xffff0000u);
    a[2] += __uint_as_float(v.y << 16);
    a[3] += __uint_as_float(v.y & 0xffff0000u);
    a[4] += __uint_as_float(v.z << 16);
    a[5] += __uint_as_float(v.z & 0xffff0000u);
    a[6] += __uint_as_float(v.w << 16);
    a[7] += __uint_as_float(v.w & 0xffff0000u);
}

// ---------------- degree (round-0 scalar form — reverted; the int4 rework was
// an unproven variable in the round-1 regression) ----------------
__global__ void deg_count(const int* __restrict__ dst, int* __restrict__ deg, int E) {
    int e = blockIdx.x * blockDim.x + threadIdx.x;
    if (e < E) atomicAdd(&deg[dst[e]], 1);
}

// ---------------- scan (3 kernels; round-9 post-mortem: single-block fused scan
// was 135 us latency-bound on one CU — multi-block version is ~5 us) ----------------
__global__ void scan1(const int* __restrict__ deg, float* __restrict__ dinv,
                      int* __restrict__ rowptr, int* __restrict__ bsum, int N) {
    __shared__ int s[256];
    int i = blockIdx.x * 256 + threadIdx.x;
    int v = (i < N) ? deg[i] : 0;
    if (i < N) dinv[i] = rsqrtf((float)(v + 1));  // +1 self-loop
    s[threadIdx.x] = v;
    __syncthreads();
    for (int off = 1; off < 256; off <<= 1) {
        int t = 0;
        if (threadIdx.x >= off) t = s[threadIdx.x - off];
        __syncthreads();
        if (threadIdx.x >= off) s[threadIdx.x] += t;
        __syncthreads();
    }
    if (i < N) rowptr[i] = s[threadIdx.x] - v;
    if (threadIdx.x == 255) bsum[blockIdx.x] = s[255];
}

__global__ void scan2(int* __restrict__ bsum, int* __restrict__ boff, int nb) {
    __shared__ int s[256];
    int v = (threadIdx.x < nb) ? bsum[threadIdx.x] : 0;
    s[threadIdx.x] = v;
    __syncthreads();
    for (int off = 1; off < 256; off <<= 1) {
        int t = 0;
        if (threadIdx.x >= off) t = s[threadIdx.x - off];
        __syncthreads();
        if (threadIdx.x >= off) s[threadIdx.x] += t;
        __syncthreads();
    }
    if (threadIdx.x < nb) boff[threadIdx.x] = s[threadIdx.x] - v;
}

__global__ void scan3(int* __restrict__ rowptr, const int* __restrict__ boff,
                      int* __restrict__ cursor, int N) {
    int i = blockIdx.x * 256 + threadIdx.x;
    if (i < N) {
        int v = rowptr[i] + boff[blockIdx.x];
        rowptr[i] = v;
        cursor[i] = v;
    }
}

// ---------------- bucket, XCD-pinned by dst partition (blockIdx&7)
// (round-0 scalar form — reverted) ----------------
__global__ __launch_bounds__(256) void bucket8(const int* __restrict__ src,
                                               const int* __restrict__ dst,
                                               int* __restrict__ cursor,
                                               int* __restrict__ csr, int E, int N) {
    int part = blockIdx.x & 7;
    int g = blockIdx.x >> 3;
    int G = gridDim.x >> 3;
    int plo = (int)(((long long)N * part) >> 3);
    int phi = (int)(((long long)N * (part + 1)) >> 3);
    for (int e = g * 256 + threadIdx.x; e < E; e += G * 256) {
        int d = dst[e];
        if (d >= plo && d < phi) {
            int pos = atomicAdd(&cursor[d], 1);
            csr[pos] = src[e];
        }
    }
}

// ---------------- GEMM1: xws1b = bf16((x @ W1) * dinv[row])   [N,128]x[128,64] -------
// k-loop bound `kb` is a RUNTIME arg so the compiler cannot fully unroll
// (round-5 post-mortem: full unroll -> 256 VGPR -> 750 MB scratch spill).
__global__ __launch_bounds__(256) void gemm1(const float* __restrict__ x,
                                             const float* __restrict__ W1,
                                             const float* __restrict__ dinv,
                                             unsigned short* __restrict__ xws1b,
                                             int N, int kb) {
    __shared__ float sx[64][132];
    __shared__ float sW[64][64];
    int tid = threadIdx.x;
    int row0 = blockIdx.x * 64;

    for (int i = tid; i < 2048; i += 256) {
        int r = i >> 5, kq = i & 31;
        int gr = row0 + r;
        float4 v = make_float4(0.f, 0.f, 0.f, 0.f);
        if (gr < N) v = ((const float4*)(x + (size_t)gr * F0))[kq];
        *(float4*)(&sx[r][kq << 2]) = v;
    }

    int tx = tid & 15, ty = tid >> 4;
    int c0 = tx * 4, r0 = ty * 4;
    float acc[4][4] = {};

    const float4* W4 = (const float4*)W1;
    float4* sW4 = (float4*)(&sW[0][0]);

    for (int p = 0; p < 2; ++p) {
        if (p) __syncthreads();
        for (int i = tid; i < 1024; i += 256) sW4[i] = W4[p * 1024 + i];
        __syncthreads();
        int kbase = p * 64;
        for (int k = 0; k < kb; k += 4) {
            float a[4][4], b[4][4];
            #pragma unroll
            for (int rr = 0; rr < 4; ++rr)
                *(float4*)&a[rr][0] = *(const float4*)&sx[r0 + rr][kbase + k];
            #pragma unroll
            for (int j = 0; j < 4; ++j)
                *(float4*)&b[j][0] = *(const float4*)&sW[k + j][c0];
            #pragma unroll
            for (int j = 0; j < 4; ++j)
                #pragma unroll
                for (int rr = 0; rr < 4; ++rr)
                    #pragma unroll
                    for (int cc = 0; cc < 4; ++cc)
                        acc[rr][cc] += a[rr][j] * b[j][cc];
        }
    }

    #pragma unroll
    for (int rr = 0; rr < 4; ++rr) {
        int gr = row0 + r0 + rr;
        if (gr < N) {
            float s = dinv[gr];
            ushort4 o;
            o.x = f2b(acc[rr][0] * s); o.y = f2b(acc[rr][1] * s);
            o.z = f2b(acc[rr][2] * s); o.w = f2b(acc[rr][3] * s);
            *(ushort4*)&xws1b[gr * F1 + c0] = o;
        }
    }
}

// ---- gather1 + gemm2 fused. Round-14: PERSISTENT blocks + pipelined node loop.
// Round-13 post-mortem: wide loads alone REGRESSED (50.4 us, VALUBusy 36%,
// HBM 9%, Occupancy 43%) — latency-bound, not issue-bound. 12.5K short blocks
// churned through W2-preload+sync faster than waves could stay resident.
// Fix: 2048 persistent blocks (8/CU x 4 waves = 32 waves/CU), W2 loaded once,
// grid-stride node loop; 2 edge-chunks of 8 in flight per iteration; self-row,
// dinv, and next node's rowptr/deg prefetched under current compute. ----
__global__ __launch_bounds__(256, 8) void gather1f(const int* __restrict__ csr,
                                                   const int* __restrict__ rowptr,
                                                   const int* __restrict__ deg,
                                                   const float* __restrict__ dinv,
                                                   const unsigned short* __restrict__ xb,
                                                   const float* __restrict__ b1,
                                                   const float* __restrict__ W2,
                                                   unsigned short* __restrict__ xws2b,
                                                   int N, int kh) {
    __shared__ float sW2[F1][F2];    // 8 KB
    __shared__ float h1s[4][F1];     // 1 KB
    int tid = threadIdx.x;
    for (int i = tid; i < (F1 * F2) / 4; i += 256)
        ((float4*)&sW2[0][0])[i] = ((const float4*)W2)[i];
    __syncthreads();

    int wv = tid >> 6, lane = tid & 63;
    int grp = lane >> 3;           // edge slot 0..7
    int fb = (lane & 7) << 3;      // feature base 0..56 (8 features/lane)
    int c = lane & 31, half = lane >> 5;
    int k0 = half * 32;
    int stride = gridDim.x * 4;

    int node = blockIdx.x * 4 + wv;
    int start = 0, cnt = 0;
    if (node < N) { start = rfl(rowptr[node]); cnt = rfl(deg[node]); }

    while (node < N) {
        // prefetch next node's CSR window under this node's work
        int nnode = node + stride;
        int nstart = 0, ncnt = 0;
        if (nnode < N) { nstart = rfl(rowptr[nnode]); ncnt = rfl(deg[nnode]); }
        float dd = dinv[node];
        uint4 vs = *(const uint4*)(xb + (size_t)node * F1 + fb);  // self row, early

        float acc[8] = {};
        for (int j = 0; j < cnt; j += 16) {
            int e0 = j + grp, e1 = e0 + 8;
            bool p0 = e0 < cnt, p1 = e1 < cnt;
            int s0 = 0, s1 = 0;
            if (p0) s0 = csr[start + e0];
            if (p1) s1 = csr[start + e1];
            uint4 v0, v1;
            if (p0) v0 = *(const uint4*)(xb + (size_t)s0 * F1 + fb);
            if (p1) v1 = *(const uint4*)(xb + (size_t)s1 * F1 + fb);
            if (p0) acc8(acc, v0);
            if (p1) acc8(acc, v1);
        }
        if (grp == 0) acc8(acc, vs);   // self-loop, exactly once

        #pragma unroll
        for (int off = 8; off < 64; off <<= 1)
            #pragma unroll
            for (int i = 0; i < 8; ++i)
                acc[i] += __shfl_xor(acc[i], off, 64);

        if (lane < 8) {   // lanes 0..7 cover all 64 features (8 each)
            float4 bA = *(const float4*)&b1[fb];
            float4 bB = *(const float4*)&b1[fb + 4];
            float4 p, q;
            p.x = fmaxf(dd * acc[0] + bA.x, 0.f);
            p.y = fmaxf(dd * acc[1] + bA.y, 0.f);
            p.z = fmaxf(dd * acc[2] + bA.z, 0.f);
            p.w = fmaxf(dd * acc[3] + bA.w, 0.f);
            q.x = fmaxf(dd * acc[4] + bB.x, 0.f);
            q.y = fmaxf(dd * acc[5] + bB.y, 0.f);
            q.z = fmaxf(dd * acc[6] + bB.z, 0.f);
            q.w = fmaxf(dd * acc[7] + bB.w, 0.f);
            *(float4*)&h1s[wv][fb] = p;
            *(float4*)&h1s[wv][fb + 4] = q;
        }

        // GEMV: h1[64] @ W2[64][32], split k across wave halves
        float d0 = 0.f, d1 = 0.f, d2 = 0.f, d3 = 0.f;
        for (int k = 0; k < kh; k += 4) {
            d0 += h1s[wv][k0 + k]     * sW2[k0 + k][c];
            d1 += h1s[wv][k0 + k + 1] * sW2[k0 + k + 1][c];
            d2 += h1s[wv][k0 + k + 2] * sW2[k0 + k + 2][c];
            d3 += h1s[wv][k0 + k + 3] * sW2[k0 + k + 3][c];
        }
        float dot = (d0 + d1) + (d2 + d3);
        dot += __shfl_down(dot, 32, 64);
        if (half == 0) xws2b[node * F2 + c] = f2b(dot * dd);

        node = nnode; start = nstart; cnt = ncnt;
    }
}

// ---- gather2 + gemm3 fused. Same persistent + pipelined structure; 4 lanes
// cover one 64 B row (uint4 each), wave covers 16 edges per load instr, two
// chunks in flight. `out` written with NON-TEMPORAL stores: write-once —
// avoid L2 RFO (round-12 counters: FETCH 35.4 MB ~ inputs + 25.6 MB out RFO). ----
__global__ __launch_bounds__(256, 8) void gather2f(const int* __restrict__ csr,
                                                   const int* __restrict__ rowptr,
                                                   const int* __restrict__ deg,
                                                   const float* __restrict__ dinv,
                                                   const unsigned short* __restrict__ xb,
                                                   const float* __restrict__ b2,
                                                   const float* __restrict__ Wl,
                                                   const float* __restrict__ bl,
                                                   float* __restrict__ out, int N, int kh) {
    __shared__ float sWl[F2][F0];    // 16 KB
    __shared__ float h2s[4][F2];     // 512 B
    int tid = threadIdx.x;
    for (int i = tid; i < (F2 * F0) / 4; i += 256)
        ((float4*)&sWl[0][0])[i] = ((const float4*)Wl)[i];
    __syncthreads();

    int wv = tid >> 6, lane = tid & 63;
    int grp = lane >> 2;           // edge slot 0..15
    int fb = (lane & 3) << 3;      // feature base 0,8,16,24 (8 features/lane)
    int stride = gridDim.x * 4;

    int node = blockIdx.x * 4 + wv;
    int start = 0, cnt = 0;
    if (node < N) { start = rfl(rowptr[node]); cnt = rfl(deg[node]); }

    while (node < N) {
        int nnode = node + stride;
        int nstart = 0, ncnt = 0;
        if (nnode < N) { nstart = rfl(rowptr[nnode]); ncnt = rfl(deg[nnode]); }
        float dd = dinv[node];
        uint4 vs = *(const uint4*)(xb + (size_t)node * F2 + fb);  // self row, early

        float acc[8] = {};
        for (int j = 0; j < cnt; j += 32) {
            int e0 = j + grp, e1 = e0 + 16;
            bool p0 = e0 < cnt, p1 = e1 < cnt;
            int s0 = 0, s1 = 0;
            if (p0) s0 = csr[start + e0];
            if (p1) s1 = csr[start + e1];
            uint4 v0, v1;
            if (p0) v0 = *(const uint4*)(xb + (size_t)s0 * F2 + fb);
            if (p1) v1 = *(const uint4*)(xb + (size_t)s1 * F2 + fb);
            if (p0) acc8(acc, v0);
            if (p1) acc8(acc, v1);
        }
        if (grp == 0) acc8(acc, vs);   // self-loop

        #pragma unroll
        for (int off = 4; off < 64; off <<= 1)
            #pragma unroll
            for (int i = 0; i < 8; ++i)
                acc[i] += __shfl_xor(acc[i], off, 64);

        if (lane < 4) {   // lanes 0..3 cover all 32 features (8 each)
            float4 bA = *(const float4*)&b2[fb];
            float4 bB = *(const float4*)&b2[fb + 4];
            float4 p, q;
            p.x = fmaxf(dd * acc[0] + bA.x, 0.f);
            p.y = fmaxf(dd * acc[1] + bA.y, 0.f);
            p.z = fmaxf(dd * acc[2] + bA.z, 0.f);
            p.w = fmaxf(dd * acc[3] + bA.w, 0.f);
            q.x = fmaxf(dd * acc[4] + bB.x, 0.f);
            q.y = fmaxf(dd * acc[5] + bB.y, 0.f);
            q.z = fmaxf(dd * acc[6] + bB.z, 0.f);
            q.w = fmaxf(dd * acc[7] + bB.w, 0.f);
            *(float4*)&h2s[wv][fb] = p;
            *(float4*)&h2s[wv][fb + 4] = q;
        }

        // final GEMV: h2[32] @ Wl[32][128] + bl
        float e0 = 0.f, e1 = 0.f, f0 = 0.f, f1 = 0.f;
        for (int k = 0; k < kh; k += 2) {
            float hk0 = h2s[wv][k], hk1 = h2s[wv][k + 1];
            e0 += hk0 * sWl[k][lane];
            e1 += hk1 * sWl[k + 1][lane];
            f0 += hk0 * sWl[k][lane + 64];
            f1 += hk1 * sWl[k + 1][lane + 64];
        }
        size_t ob = (size_t)node * F0;
        __builtin_nontemporal_store((e0 + e1) + bl[lane],      &out[ob + lane]);
        __builtin_nontemporal_store((f0 + f1) + bl[lane + 64], &out[ob + lane + 64]);

        node = nnode; start = nstart; cnt = ncnt;
    }
}

extern "C" void kernel_launch(void* const* d_in, const int* in_sizes, int n_in,
                              void* d_out, int out_size, void* d_ws, size_t ws_size,
                              hipStream_t stream) {
    const float* x  = (const float*)d_in[0];
    const int*   ei = (const int*)d_in[1];
    const float* W1 = (const float*)d_in[2];
    const float* b1 = (const float*)d_in[3];
    const float* W2 = (const float*)d_in[4];
    const float* b2 = (const float*)d_in[5];
    const float* Wl = (const float*)d_in[6];
    const float* bl = (const float*)d_in[7];
    float* out = (float*)d_out;

    const int N = in_sizes[0] / F0;   // 50000
    const int E = in_sizes[1] / 2;    // 800000
    const int* src = ei;
    const int* dst = ei + E;
    const int NB = (N + 255) / 256;   // 196

    char* ws = (char*)d_ws;
    size_t off = 0;
    auto alloc = [&](size_t bytes) {
        void* p = ws + off;
        off += (bytes + 255) & ~(size_t)255;
        return p;
    };
    int*            deg    = (int*)alloc((size_t)N * 4);
    float*          dinv   = (float*)alloc((size_t)N * 4);
    int*            rowptr = (int*)alloc((size_t)N * 4);
    int*            cursor = (int*)alloc((size_t)N * 4);
    int*            bsum   = (int*)alloc((size_t)NB * 4);
    int*            boff   = (int*)alloc((size_t)NB * 4);
    int*            csr    = (int*)alloc((size_t)E * 4);
    unsigned short* xws1b  = (unsigned short*)alloc((size_t)N * F1 * 2);
    unsigned short* xws2b  = (unsigned short*)alloc((size_t)N * F2 * 2);

    hipMemsetAsync(deg, 0, (size_t)N * 4, stream);
    deg_count<<<(E + 255) / 256, 256, 0, stream>>>(dst, deg, E);
    scan1<<<NB, 256, 0, stream>>>(deg, dinv, rowptr, bsum, N);
    scan2<<<1, 256, 0, stream>>>(bsum, boff, NB);
    scan3<<<NB, 256, 0, stream>>>(rowptr, boff, cursor, N);
    bucket8<<<1024, 256, 0, stream>>>(src, dst, cursor, csr, E, N);

    gemm1<<<(N + 63) / 64, 256, 0, stream>>>(x, W1, dinv, xws1b, N, 64);
    gather1f<<<2048, 256, 0, stream>>>(csr, rowptr, deg, dinv, xws1b, b1, W2, xws2b, N, 32);
    gather2f<<<2048, 256, 0, stream>>>(csr, rowptr, deg, dinv, xws2b, b2, Wl, bl, out, N, 32);
}